// Round 4
// baseline (93.832 us; speedup 1.0000x reference)
//
#include <hip/hip_runtime.h>

// LIF forward: y_t = heaviside(v_{t-1}*tau + x_t - v_th), hard reset.
// x: [T=16, N=4194304] f32. Independent per spatial element; scan only in T.
//
// Findings so far (R0-R3):
//  - FETCH_SIZE identical (131 MB = x/2) under plain vs nt stores => y writes
//    do NOT allocate in L3; the fetch is x self-thrash at exactly L3 capacity.
//    Store-policy tricks cannot reduce it. (R3's asm sc0sc1nt store also broke
//    correctness -> reverted to the builtin.)
//  - VGPR=36 in R2 => compiler sank the 16 preloads (only ~5-6 in flight).
//    Read-side MLP is the limiter (4.6 of 6.3 TB/s). This round pins all 16
//    loads before a scheduler+compiler barrier so each wave holds 16
//    outstanding global_load_dwordx4 (256 B in flight/wave, ~6 KB/CU at
//    24 waves/CU).
#define TAU 0.5f
#define V_TH 1.0f

typedef __attribute__((ext_vector_type(4))) float f32x4;

__global__ __launch_bounds__(256) void lif_fwd_kernel(
    const f32x4* __restrict__ x, f32x4* __restrict__ y, int n4) {
    int i = blockIdx.x * blockDim.x + threadIdx.x;
    if (i >= n4) return;

    const f32x4* xp = x + i;
    f32x4* yp = y + i;

    // Issue ALL 16 timestep loads; barrier below forbids sinking them.
    f32x4 xv[16];
#pragma unroll
    for (int t = 0; t < 16; ++t)
        xv[t] = xp[(size_t)t * n4];

    // IR-level memory barrier + MIR-level scheduler barrier: no load may be
    // deferred past this point, so all 16 stay in flight (64 payload VGPRs).
    asm volatile("" ::: "memory");
    __builtin_amdgcn_sched_barrier(0);

    f32x4 v = (f32x4)0.f;
#pragma unroll
    for (int t = 0; t < 16; ++t) {
        f32x4 m, yv;
        // tau = 0.5: v*0.5 exact, so fma-or-not matches JAX bitwise.
        m.x = v.x * TAU + xv[t].x;
        m.y = v.y * TAU + xv[t].y;
        m.z = v.z * TAU + xv[t].z;
        m.w = v.w * TAU + xv[t].w;
        yv.x = (m.x - V_TH > 0.f) ? 1.f : 0.f;
        yv.y = (m.y - V_TH > 0.f) ? 1.f : 0.f;
        yv.z = (m.z - V_TH > 0.f) ? 1.f : 0.f;
        yv.w = (m.w - V_TH > 0.f) ? 1.f : 0.f;
        v.x = (yv.x > 0.f) ? 0.f : m.x;
        v.y = (yv.y > 0.f) ? 0.f : m.y;
        v.z = (yv.z > 0.f) ? 0.f : m.z;
        v.w = (yv.w > 0.f) ? 0.f : m.w;
        __builtin_nontemporal_store(yv, &yp[(size_t)t * n4]);
    }
}

extern "C" void kernel_launch(void* const* d_in, const int* in_sizes, int n_in,
                              void* d_out, int out_size, void* d_ws, size_t ws_size,
                              hipStream_t stream) {
    const float* x = (const float*)d_in[0];
    float* y = (float*)d_out;

    const int T = 16;
    const long long total = (long long)in_sizes[0];   // 67,108,864
    const int N = (int)(total / T);                   // 4,194,304 per timestep
    const int n4 = N / 4;                             // 1,048,576 float4 columns

    dim3 block(256);
    dim3 grid((n4 + 255) / 256);
    lif_fwd_kernel<<<grid, block, 0, stream>>>(
        (const f32x4*)x, (f32x4*)y, n4);
}

// Round 5
// 86.661 us; speedup vs baseline: 1.0827x; 1.0827x over previous
//
#include <hip/hip_runtime.h>

// LIF forward: y_t = heaviside(v_{t-1}*tau + x_t - v_th), hard reset.
// x: [T=16, N=4194304] f32. Independent per spatial element; scan only in T.
//
// Final structure (= R2, best measured 85.8 us). Session findings:
//  - R0 loop-carried load->compute->store serialization: 123 us.
//  - Preloading the 16 timestep quads breaks that chain: 85.8 us (R2).
//  - FETCH_SIZE is bit-identical (131 MB = x/2) under plain / nt / asm-nt
//    stores => y never allocates in L3; the fetch is x self-thrash at
//    exactly L3 capacity. Store-policy tricks are a dead lever.
//  - MLP is NOT the limiter (>=5 outstanding 1KB loads/wave x 21 waves/CU
//    ~ 126 KB/CU in flight >> ~9 KB needed). sched_barrier pinning only
//    regressed (93.8 us, R4).
//  - Roofline: fabric traffic = 268 MB x-reads + 268 MB y-writes = 536 MB
//    (L3 hits save HBM bytes, not fabric bytes) at ~6.3 TB/s => 85.1 us.
//    R2 = 85.8 us = 99% of it.
#define TAU 0.5f
#define V_TH 1.0f

typedef __attribute__((ext_vector_type(4))) float f32x4;

__global__ __launch_bounds__(256) void lif_fwd_kernel(
    const f32x4* __restrict__ x, f32x4* __restrict__ y, int n4) {
    int i = blockIdx.x * blockDim.x + threadIdx.x;
    if (i >= n4) return;

    const f32x4* xp = x + i;
    f32x4* yp = y + i;

    // Independent per-timestep loads, issued ahead of the v-chain.
    f32x4 xv[16];
#pragma unroll
    for (int t = 0; t < 16; ++t)
        xv[t] = xp[(size_t)t * n4];

    f32x4 v = (f32x4)0.f;
#pragma unroll
    for (int t = 0; t < 16; ++t) {
        f32x4 m, yv;
        // tau = 0.5: v*0.5 exact, so fma-or-not matches JAX bitwise.
        m.x = v.x * TAU + xv[t].x;
        m.y = v.y * TAU + xv[t].y;
        m.z = v.z * TAU + xv[t].z;
        m.w = v.w * TAU + xv[t].w;
        yv.x = (m.x - V_TH > 0.f) ? 1.f : 0.f;
        yv.y = (m.y - V_TH > 0.f) ? 1.f : 0.f;
        yv.z = (m.z - V_TH > 0.f) ? 1.f : 0.f;
        yv.w = (m.w - V_TH > 0.f) ? 1.f : 0.f;
        v.x = (yv.x > 0.f) ? 0.f : m.x;
        v.y = (yv.y > 0.f) ? 0.f : m.y;
        v.z = (yv.z > 0.f) ? 0.f : m.z;
        v.w = (yv.w > 0.f) ? 0.f : m.w;
        __builtin_nontemporal_store(yv, &yp[(size_t)t * n4]);
    }
}

extern "C" void kernel_launch(void* const* d_in, const int* in_sizes, int n_in,
                              void* d_out, int out_size, void* d_ws, size_t ws_size,
                              hipStream_t stream) {
    const float* x = (const float*)d_in[0];
    float* y = (float*)d_out;

    const int T = 16;
    const long long total = (long long)in_sizes[0];   // 67,108,864
    const int N = (int)(total / T);                   // 4,194,304 per timestep
    const int n4 = N / 4;                             // 1,048,576 float4 columns

    dim3 block(256);
    dim3 grid((n4 + 255) / 256);
    lif_fwd_kernel<<<grid, block, 0, stream>>>(
        (const f32x4*)x, (f32x4*)y, n4);
}